// Round 16
// baseline (403.676 us; speedup 1.0000x reference)
//
#include <hip/hip_runtime.h>
#include <hip/hip_bf16.h>
#include <stdint.h>

#define M_TOTAL 16384   // BATCH * SEQ
#define N_TOTAL 4096    // OUT_FEATURES
#define K_TOTAL 4096    // IN_FEATURES

#define BM 256
#define BN 256
#define BKI 64                   // int8 K per step
#define NTI (K_TOTAL / BKI)      // 64 K-steps

typedef __attribute__((ext_vector_type(4))) float f32x4;
typedef __attribute__((ext_vector_type(4))) int   i32x4;

// ---------- x fp32 -> int8 per-row quant, MFMA-frag-packed (r10-proven). ----
// Apk unit: [m16][kc][lane] 16 B; lane l holds row m16*16+(l&15),
// k = kc*64 + (l>>4)*16.
__global__ __launch_bounds__(256) void quant_x_kernel(
    const float* __restrict__ x, signed char* __restrict__ Apk,
    float* __restrict__ qrow) {
  __shared__ float red[8];
  __shared__ int   sq[1024];                       // 4 KB staging
  const int blk = blockIdx.x;
  const int row = (blk & 7) * 2048 + (blk >> 3);
  const int tid = threadIdx.x;
  const float* xr = x + (size_t)row * K_TOTAL;
  const f32x4* xv = (const f32x4*)xr;

  f32x4 v[4];
  float mx = 0.f;
#pragma unroll
  for (int j = 0; j < 4; ++j) {
    v[j] = xv[j * 256 + tid];                      // coalesced float4
#pragma unroll
    for (int e = 0; e < 4; ++e) mx = fmaxf(mx, fabsf(v[j][e]));
  }
#pragma unroll
  for (int off = 32; off > 0; off >>= 1) mx = fmaxf(mx, __shfl_xor(mx, off));
  if ((tid & 63) == 0) red[tid >> 6] = mx;
  __syncthreads();
  if (tid == 0) {
    float m2 = fmaxf(fmaxf(red[0], red[1]), fmaxf(red[2], red[3]));
    red[4] = m2;
    qrow[row] = m2 * (1.f / 127.f);
  }
  __syncthreads();
  const float rmax = red[4];
  const float rq = rmax > 0.f ? 127.f / rmax : 0.f;

#pragma unroll
  for (int j = 0; j < 4; ++j) {
    int b0 = (int)rintf(v[j][0] * rq) & 0xff;
    int b1 = (int)rintf(v[j][1] * rq) & 0xff;
    int b2 = (int)rintf(v[j][2] * rq) & 0xff;
    int b3 = (int)rintf(v[j][3] * rq) & 0xff;
    sq[j * 256 + tid] = b0 | (b1 << 8) | (b2 << 16) | (b3 << 24);  // k-linear
  }
  __syncthreads();
  const i32x4 o = ((const i32x4*)sq)[tid];         // bytes tid*16..+15
  i32x4* outp = (i32x4*)(Apk + (size_t)(row >> 4) * 65536);
  outp[(tid >> 2) * 64 + ((tid & 3) << 4) + (row & 15)] = o;
}

// ---------- packed int4 -> int8, MFMA-frag-packed B. ----------
// Bpk unit u: lane = u&63, kc = (u>>6)&63, o16 = u>>12. Holds W row
// o = o16*16+(lane&15), k-bytes kc*64+(lane>>4)*16 .. +15.
__global__ __launch_bounds__(256) void dequant_pack_kernel(
    const int* __restrict__ wq, signed char* __restrict__ Bp) {
  const int u0 = (blockIdx.x * 256 + threadIdx.x) * 4;
#pragma unroll
  for (int i = 0; i < 4; ++i) {
    const int u = u0 + i;                 // < 1048576
    const int lane = u & 63;
    const int kc = (u >> 6) & 63;
    const int o16 = u >> 12;              // 0..255
    const int o = o16 * 16 + (lane & 15);
    const int k = kc * 64 + (lane >> 4) * 16;
    const int* src = wq + (size_t)o * (K_TOTAL / 2) + (k >> 1);   // 8 ints
    i32x4 s0 = *(const i32x4*)src;
    i32x4 s1 = *(const i32x4*)(src + 4);
    int wds[4];
#pragma unroll
    for (int h = 0; h < 2; ++h) {
      i32x4 s = h ? s1 : s0;
#pragma unroll
      for (int p = 0; p < 2; ++p) {
        int ba = s[2 * p], bb = s[2 * p + 1];
        int lo0 = (((ba & 0xF) ^ 8) - 8) & 0xff;
        int hi0 = ((((ba >> 4) & 0xF) ^ 8) - 8) & 0xff;
        int lo1 = (((bb & 0xF) ^ 8) - 8) & 0xff;
        int hi1 = ((((bb >> 4) & 0xF) ^ 8) - 8) & 0xff;
        wds[h * 2 + p] = lo0 | (hi0 << 8) | (lo1 << 16) | (hi1 << 24);
      }
    }
    i32x4 o4; o4[0] = wds[0]; o4[1] = wds[1]; o4[2] = wds[2]; o4[3] = wds[3];
    *(i32x4*)(Bp + (size_t)u * 16) = o4;
  }
}

#define MFMAI(a, b, c) __builtin_amdgcn_mfma_i32_16x16x64_i8((a), (b), (c), 0, 0, 0)
#define SCHED0() __builtin_amdgcn_sched_barrier(0)

// int8 GEMM: 256x256, 8 waves (2x4). BARRIERLESS, LDS-FREE: both operands
// frag-packed in global; each wave register-double-buffers A(8)+B(4) frags,
// loaded 1 tile ahead as coalesced 1KB loads (L2-resident via bn-fastest XCD
// map). Per tile: vmcnt(12) [drains tile t; t+1 in flight] -> 32 MFMA ->
// issue loads(t+2). No s_barrier, no ds_read: waves fully independent, so
// the matrix pipe never waits on the (removed) shared DS unit — attacks the
// 10-variant 44% phase-lock by removing the coupling resource.
__global__ __launch_bounds__(512, 2) void gemm256_i8_kernel(
    const signed char* __restrict__ Apk,  // frag-packed A
    const signed char* __restrict__ Bpk,  // frag-packed B
    const float* __restrict__ qrow,
    const float* __restrict__ scales,
    const float* __restrict__ bias,
    float* __restrict__ C) {
  const int t  = threadIdx.x;
  const int l  = t & 63;
  const int w  = t >> 6;
  const int wm = w >> 2;        // 0..1 (128-row band)
  const int wn = w & 3;         // 0..3 (64-col band)
  const int fr = l & 15;
  const int kg = l >> 4;        // 0..3

  // XCD map, bn-fastest within each XCD so concurrent blocks share bm
  // (~2 MB A working set per XCD L2). nwg = 1024, wg&7 = XCD.
  const int wg = blockIdx.x;
  const int bm = (wg & 7) * 8 + (wg >> 7);          // 0..63
  const int bn = (wg >> 3) & 15;                    // 0..15

  // Per-wave packed bases: frag (mf|nf, kc) at base + frag*65536 + kc*1024.
  const signed char* pA = Apk + (size_t)(bm * 16 + wm * 8) * 65536 + l * 16;
  const signed char* pB = Bpk + (size_t)(bn * 16 + wn * 4) * 65536 + l * 16;

  i32x4 acc[8][4] = {};
  i32x4 aE[8], bE[4], aO[8], bO[4];

  // Prologue: tiles 0 (E) and 1 (O); 24 loads in flight max.
#pragma unroll
  for (int mf = 0; mf < 8; ++mf) aE[mf] = *(const i32x4*)(pA + (size_t)mf * 65536);
#pragma unroll
  for (int nf = 0; nf < 4; ++nf) bE[nf] = *(const i32x4*)(pB + (size_t)nf * 65536);
#pragma unroll
  for (int mf = 0; mf < 8; ++mf) aO[mf] = *(const i32x4*)(pA + (size_t)mf * 65536 + 1024);
#pragma unroll
  for (int nf = 0; nf < 4; ++nf) bO[nf] = *(const i32x4*)(pB + (size_t)nf * 65536 + 1024);
  SCHED0();

  for (int t0 = 0; t0 < NTI; t0 += 2) {
    // ---- even tile t0 (bufs E) ----
    asm volatile("s_waitcnt vmcnt(12)" ::: "memory");  // tile t0's 12 landed
    SCHED0();
    __builtin_amdgcn_s_setprio(1);
#pragma unroll
    for (int mf = 0; mf < 8; ++mf)
#pragma unroll
      for (int nf = 0; nf < 4; ++nf)
        acc[mf][nf] = MFMAI(aE[mf], bE[nf], acc[mf][nf]);
    __builtin_amdgcn_s_setprio(0);
    SCHED0();
    if (t0 + 2 < NTI) {
      const size_t ko = (size_t)(t0 + 2) << 10;
#pragma unroll
      for (int mf = 0; mf < 8; ++mf) aE[mf] = *(const i32x4*)(pA + (size_t)mf * 65536 + ko);
#pragma unroll
      for (int nf = 0; nf < 4; ++nf) bE[nf] = *(const i32x4*)(pB + (size_t)nf * 65536 + ko);
    }
    SCHED0();

    // ---- odd tile t0+1 (bufs O) ----
    if (t0 + 1 == NTI - 1) { asm volatile("s_waitcnt vmcnt(0)" ::: "memory"); }
    else                   { asm volatile("s_waitcnt vmcnt(12)" ::: "memory"); }
    SCHED0();
    __builtin_amdgcn_s_setprio(1);
#pragma unroll
    for (int mf = 0; mf < 8; ++mf)
#pragma unroll
      for (int nf = 0; nf < 4; ++nf)
        acc[mf][nf] = MFMAI(aO[mf], bO[nf], acc[mf][nf]);
    __builtin_amdgcn_s_setprio(0);
    SCHED0();
    if (t0 + 3 < NTI) {
      const size_t ko = (size_t)(t0 + 3) << 10;
#pragma unroll
      for (int mf = 0; mf < 8; ++mf) aO[mf] = *(const i32x4*)(pA + (size_t)mf * 65536 + ko);
#pragma unroll
      for (int nf = 0; nf < 4; ++nf) bO[nf] = *(const i32x4*)(pB + (size_t)nf * 65536 + ko);
    }
    SCHED0();
  }

  // Epilogue: C/D layout col = lane&15, row = (lane>>4)*4 + reg (dtype-indep).
  const int row0 = bm * BM + wm * 128 + kg * 4;
  const int col0 = bn * BN + wn * 64 + fr;
  float qv[8][4];
#pragma unroll
  for (int m = 0; m < 8; ++m)
#pragma unroll
    for (int r = 0; r < 4; ++r) qv[m][r] = qrow[row0 + m * 16 + r];
#pragma unroll
  for (int nf = 0; nf < 4; ++nf) {
    const int gc = col0 + nf * 16;
    const float s  = scales[gc];
    const float bv = bias[gc];
#pragma unroll
    for (int m = 0; m < 8; ++m) {
      const int gr = row0 + m * 16;
#pragma unroll
      for (int r = 0; r < 4; ++r)
        C[(size_t)(gr + r) * N_TOTAL + gc] = (float)acc[m][nf][r] * (qv[m][r] * s) + bv;
    }
  }
}

// Fallback if workspace is too small: correct but slow.
__global__ void naive_int4_kernel(const float* __restrict__ x,
                                  const int* __restrict__ wq,
                                  const float* __restrict__ scales,
                                  const float* __restrict__ bias,
                                  float* __restrict__ out) {
  size_t idx = (size_t)blockIdx.x * blockDim.x + threadIdx.x;
  int o = (int)(idx & (N_TOTAL - 1));
  int m = (int)(idx >> 12);
  const float* xr = x + (size_t)m * K_TOTAL;
  const int* wrow = wq + (size_t)o * (K_TOTAL / 2);
  float acc = 0.f;
  for (int j = 0; j < K_TOTAL / 2; ++j) {
    int b = wrow[j];
    int lo = ((b & 0xF) ^ 8) - 8;
    int hi = (((b >> 4) & 0xF) ^ 8) - 8;
    acc += xr[2 * j] * (float)lo + xr[2 * j + 1] * (float)hi;
  }
  out[idx] = acc * scales[o] + bias[o];
}

extern "C" void kernel_launch(void* const* d_in, const int* in_sizes, int n_in,
                              void* d_out, int out_size, void* d_ws, size_t ws_size,
                              hipStream_t stream) {
  const float* x      = (const float*)d_in[0];
  const int*   wq     = (const int*)d_in[1];
  const float* scales = (const float*)d_in[2];
  const float* bias   = (const float*)d_in[3];
  float* out = (float*)d_out;

  const size_t needXQ = (size_t)M_TOTAL * K_TOTAL;                 // 67.1 MB
  const size_t needW8 = (size_t)N_TOTAL * K_TOTAL;                 // 16.8 MB
  const size_t needQ  = (size_t)M_TOTAL * sizeof(float);           // 64 KB

  if (d_ws != nullptr && ws_size >= needXQ + needW8 + needQ) {
    signed char* apk = (signed char*)d_ws;
    signed char* bpk = (signed char*)d_ws + needXQ;
    float* qrow = (float*)((char*)d_ws + needXQ + needW8);
    quant_x_kernel<<<M_TOTAL, 256, 0, stream>>>(x, apk, qrow);
    dequant_pack_kernel<<<1024, 256, 0, stream>>>(wq, bpk);
    gemm256_i8_kernel<<<(M_TOTAL / BM) * (N_TOTAL / BN), 512, 0, stream>>>(
        apk, bpk, qrow, scales, bias, out);
  } else {
    const size_t total = (size_t)M_TOTAL * N_TOTAL;
    naive_int4_kernel<<<(unsigned)(total / 256), 256, 0, stream>>>(x, wq, scales, bias, out);
  }
}